// Round 13
// baseline (169.565 us; speedup 1.0000x reference)
//
#include <hip/hip_runtime.h>
#include <hip/hip_bf16.h>
#include <math.h>

// ---------------------------------------------------------------------------
// GCN forward: 2x GCNConv + global_add_pool + MLP + log_softmax.
// R13 = R12 with two changes:
//  - hipMemsetAsync(bcnt) replaced by k_zero kernel (profile showed recurring
//    ~40us fillBufferAligned dispatches writing only ~16KB - suspected
//    in-graph tiny-fill overhead).
//  - SCAT_CHUNK 2048->1024 (782 scatter blocks).
// Pipeline (7 launches):
//   k_zero -> k_front(scatter || wprep) -> k_g1csr(gemm1-f32 || bcsr)
//   -> agg1 -> k_mid(gemm2 || pool1) -> agg2 -> k_mlp(pool2 + MLP + lsm)
// GEMMs write UNSCALED XW bf16; aggregate gathers dinv[s] per edge.
// ---------------------------------------------------------------------------

#define DIMH 128
#define EBCAP 8192   // per-bucket capacity (avg fill 4096)
#define SCAT_CHUNK 1024

typedef __attribute__((ext_vector_type(8))) short s16x8;
typedef __attribute__((ext_vector_type(4))) float f32x4;

__device__ inline ushort f2b(float f) {            // f32 -> bf16 RNE
    uint u = __float_as_uint(f);
    return (ushort)((u + 0x7fffu + ((u >> 16) & 1u)) >> 16);
}
__device__ inline uint pack2(float lo, float hi) {
    return (uint)f2b(lo) | ((uint)f2b(hi) << 16);
}
__device__ inline float blo(uint u) { return __uint_as_float(u << 16); }
__device__ inline float bhi(uint u) { return __uint_as_float(u & 0xffff0000u); }

// zero the 256 bucket counters (replaces hipMemsetAsync)
__global__ __launch_bounds__(256) void k_zero(int* __restrict__ bcnt) {
    bcnt[threadIdx.x] = 0;
}

// ---- front: scatter || wprep ----------------------------------------------
// bucket = dst>>8, record = (dst&255)<<24 | src   (needs N < 2^24)
__global__ __launch_bounds__(256) void k_front(const int* __restrict__ src,
                                               const int* __restrict__ dst,
                                               int* __restrict__ bcnt,
                                               uint* __restrict__ ebuf, int E, int scnb,
                                               const float* __restrict__ W1,
                                               const float* __restrict__ W2,
                                               ushort* __restrict__ WT1,
                                               ushort* __restrict__ WT2) {
    __shared__ int h[4][256];    // per-wave histogram / rank counters
    __shared__ int wb[4][256];   // per-wave bucket bases
    int blk = blockIdx.x;
    int t = threadIdx.x;
    if (blk < scnb) {
        int wave = t >> 6;
        h[0][t] = 0; h[1][t] = 0; h[2][t] = 0; h[3][t] = 0;
        __syncthreads();
        int e0 = blk * SCAT_CHUNK;
        int e1 = e0 + SCAT_CHUNK; if (e1 > E) e1 = E;
        for (int e = e0 + t; e < e1; e += 256)
            atomicAdd(&h[wave][dst[e] >> 8], 1);
        __syncthreads();
        {
            int h0 = h[0][t], h1 = h[1][t], h2 = h[2][t], h3 = h[3][t];
            int tot = h0 + h1 + h2 + h3;
            int gb = tot ? atomicAdd(&bcnt[t], tot) : 0;
            wb[0][t] = gb;
            wb[1][t] = gb + h0;
            wb[2][t] = gb + h0 + h1;
            wb[3][t] = gb + h0 + h1 + h2;
            h[0][t] = 0; h[1][t] = 0; h[2][t] = 0; h[3][t] = 0;
        }
        __syncthreads();
        for (int e = e0 + t; e < e1; e += 256) {
            int d = dst[e];
            int bk = d >> 8;
            int rank = wb[wave][bk] + atomicAdd(&h[wave][bk], 1);
            if (rank < EBCAP)
                ebuf[(size_t)bk * EBCAP + rank] = ((uint)(d & 255) << 24) | (uint)src[e];
        }
    } else {
        // ---- W1,W2 [128k][128n] f32 -> WT [128n][128k] bf16 ----
        int idx = (blk - scnb) * 256 + t;   // 128 blocks -> 32768
        const float* W = (idx < 16384) ? W1 : W2;
        ushort* WT = (idx < 16384) ? WT1 : WT2;
        int tt = idx & 16383;
        int k = tt >> 7, nn = tt & 127;
        WT[nn * 128 + k] = f2b(W[tt]);
    }
}

// ---- bcsr body: deg/dinv + local scan -> rng(int2) + dense srt ------------
__device__ __forceinline__ void bcsr_body(const uint* __restrict__ ebuf,
                                          const int* __restrict__ bcnt,
                                          float* __restrict__ dinv,
                                          int2* __restrict__ rng,
                                          int* __restrict__ srt, int n,
                                          int b, int* cnt, int* wsum, int* stage) {
    int t = threadIdx.x;
    int c = bcnt[b]; if (c > EBCAP) c = EBCAP;
    size_t B = (size_t)b * EBCAP;
    cnt[t] = 0;
    __syncthreads();
    for (int i = t; i < c; i += 256)
        atomicAdd(&cnt[ebuf[B + i] >> 24], 1);
    __syncthreads();
    int v = cnt[t];
    int incl = v;
    for (int k = 1; k < 64; k <<= 1) {
        int u = __shfl_up(incl, k, 64);
        if ((t & 63) >= k) incl += u;
    }
    if ((t & 63) == 63) wsum[t >> 6] = incl;
    __syncthreads();
    int add = 0;
    for (int j = 0; j < (t >> 6); ++j) add += wsum[j];
    incl += add;
    int loc = incl - v;
    int node = b * 256 + t;
    if (node < n) {
        dinv[node] = rsqrtf((float)(v + 1));   // +1 self-loop
        rng[node] = make_int2((int)B + loc, (int)B + loc + v);
    }
    cnt[t] = loc;                    // reuse as cursor
    __syncthreads();
    for (int i = t; i < c; i += 256) {
        uint r = ebuf[B + i];
        int p = atomicAdd(&cnt[r >> 24], 1);
        stage[p] = (int)(r & 0xffffffu);
    }
    __syncthreads();
    for (int i = t; i < c; i += 256) srt[B + i] = stage[i];
}

// ---- GEMM body: P[64 rows][128] bf16 = Xin @ W (UNSCALED), WT[n][k] -------
template<bool F32IN>
__device__ __forceinline__ void gemm_body(const void* __restrict__ Xin,
                                          const ushort* __restrict__ WT,
                                          ushort* __restrict__ P, int n,
                                          int blk, ushort* lds) {
    ushort* Xs = lds;
    ushort* Ws = lds + 64 * 128;
    const int tid = threadIdx.x;
    const int row0 = blk * 64;
    if (F32IN) {
        const float* Xf = (const float*)Xin;
        for (int ci = tid; ci < 2048; ci += 256) {
            int r = ci >> 5, c8 = ci & 31;
            uint dstB = (uint)(r * 256 + c8 * 8) ^ (uint)((r & 7) << 4);
            uint2 v = make_uint2(0u, 0u);
            if (row0 + r < n) {
                float4 f = *(const float4*)(Xf + (size_t)(row0 + r) * 128 + c8 * 4);
                v.x = pack2(f.x, f.y); v.y = pack2(f.z, f.w);
            }
            *(uint2*)((char*)Xs + dstB) = v;
        }
    } else {
        const ushort* Xb = (const ushort*)Xin;
        for (int ci = tid; ci < 1024; ci += 256) {
            int r = ci >> 4, c16 = ci & 15;
            uint dstB = (uint)(r * 256 + c16 * 16) ^ (uint)((r & 7) << 4);
            uint4 v = make_uint4(0u, 0u, 0u, 0u);
            if (row0 + r < n) v = *(const uint4*)(Xb + (size_t)(row0 + r) * 128 + c16 * 8);
            *(uint4*)((char*)Xs + dstB) = v;
        }
    }
    for (int ci = tid; ci < 2048; ci += 256) {
        int r = ci >> 4, c16 = ci & 15;
        uint dstB = (uint)(r * 256 + c16 * 16) ^ (uint)((r & 7) << 4);
        *(uint4*)((char*)Ws + dstB) = *(const uint4*)(WT + (size_t)r * 128 + c16 * 8);
    }
    __syncthreads();
    const int wave = tid >> 6, lane = tid & 63;
    const int l15 = lane & 15, g = lane >> 4;
    f32x4 acc[8];
#pragma unroll
    for (int nt = 0; nt < 8; ++nt) acc[nt] = (f32x4){0.f, 0.f, 0.f, 0.f};
    const int tr = wave * 16 + l15;
    const uint aswz = (uint)((tr & 7) << 4);
#pragma unroll
    for (int kk = 0; kk < 4; ++kk) {
        uint aB = ((uint)(tr * 256 + kk * 64 + g * 16)) ^ aswz;
        s16x8 afrag = *(const s16x8*)((const char*)Xs + aB);
#pragma unroll
        for (int nt = 0; nt < 8; ++nt) {
            int wr = nt * 16 + l15;
            uint bB = ((uint)(wr * 256 + kk * 64 + g * 16)) ^ ((uint)((wr & 7) << 4));
            s16x8 bfrag = *(const s16x8*)((const char*)Ws + bB);
            acc[nt] = __builtin_amdgcn_mfma_f32_16x16x32_bf16(afrag, bfrag, acc[nt], 0, 0, 0);
        }
    }
#pragma unroll
    for (int nt = 0; nt < 8; ++nt) {
        int gcol = nt * 16 + l15;
#pragma unroll
        for (int reg = 0; reg < 4; ++reg) {
            int grow = row0 + wave * 16 + g * 4 + reg;
            if (grow < n) P[(size_t)grow * 128 + gcol] = f2b(acc[nt][reg]);
        }
    }
}

// ---- g1csr: gemm1 (f32 input, blocks < gemnb) || bcsr ---------------------
__global__ __launch_bounds__(256) void k_g1csr(const float* __restrict__ x,
                                               const ushort* __restrict__ WT1,
                                               ushort* __restrict__ P, int n, int gemnb,
                                               const uint* __restrict__ ebuf,
                                               const int* __restrict__ bcnt,
                                               float* __restrict__ dinv,
                                               int2* __restrict__ rng,
                                               int* __restrict__ srt) {
    __shared__ ushort lds[64 * 128 + 128 * 128];   // 48KB; bcsr carves from it
    int blk = blockIdx.x;
    if (blk < gemnb) {
        gemm_body<true>(x, WT1, P, n, blk, lds);
    } else {
        int* cnt   = (int*)lds;          // 256 ints
        int* wsum  = cnt + 256;          // 8 ints
        int* stage = wsum + 8;           // EBCAP ints
        bcsr_body(ebuf, bcnt, dinv, rng, srt, n, blk - gemnb, cnt, wsum, stage);
    }
}

// ---- pool body: block = (graph g, quarter q); 8 row-streams, stride 8 -----
__device__ __forceinline__ void pool_body(const ushort* __restrict__ Hb,
                                          const int* __restrict__ batch,
                                          float* __restrict__ Gpart, int n,
                                          int blk, int* range, float* part) {
    int g = blk >> 2, q = blk & 3;
    if (threadIdx.x < 2) {
        int target = g + threadIdx.x;
        int lo = 0, hi = n;
        while (lo < hi) { int m = (lo + hi) >> 1; if (batch[m] < target) lo = m + 1; else hi = m; }
        range[threadIdx.x] = lo;
    }
    __syncthreads();
    int c = threadIdx.x & 127, h = threadIdx.x >> 7;
    int r = range[0] + q * 2 + h, r1 = range[1];
    float s0 = 0.f, s1 = 0.f;
    for (; r + 8 < r1; r += 16) {
        s0 += __uint_as_float((uint)Hb[(size_t)r       * 128 + c] << 16);
        s1 += __uint_as_float((uint)Hb[(size_t)(r + 8) * 128 + c] << 16);
    }
    for (; r < r1; r += 8) s0 += __uint_as_float((uint)Hb[(size_t)r * 128 + c] << 16);
    part[threadIdx.x] = s0 + s1;
    __syncthreads();
    if (threadIdx.x < 128)
        Gpart[(size_t)blk * 128 + threadIdx.x] = part[threadIdx.x] + part[threadIdx.x + 128];
}

// ---- mid: gemm2 (bf16 input, blocks < gemnb) || pool1 ---------------------
__global__ __launch_bounds__(256) void k_mid(const ushort* __restrict__ Hb,
                                             const ushort* __restrict__ WT,
                                             ushort* __restrict__ P, int n, int gemnb,
                                             const int* __restrict__ batch,
                                             float* __restrict__ Gpart) {
    __shared__ ushort lds[64 * 128 + 128 * 128];   // 48KB (gemm path)
    __shared__ int range[2];
    __shared__ float part[256];
    int blk = blockIdx.x;
    if (blk < gemnb) {
        gemm_body<false>(Hb, WT, P, n, blk, lds);
    } else {
        pool_body(Hb, batch, Gpart, n, blk - gemnb, range, part);
    }
}

// H[i] = bf16( dinv[i]*(dinv[i]*P[i] + sum_s dinv[s]*P[s]) + bias ).
// P bf16 UNSCALED, 256B/row; dinv gathered per edge (L2-resident, 200KB).
__global__ __launch_bounds__(256) void k_aggregate(const ushort* __restrict__ Pb,
                                                   const int2* __restrict__ rng,
                                                   const int* __restrict__ srt,
                                                   const float* __restrict__ dinv,
                                                   const float* __restrict__ bias,
                                                   ushort* __restrict__ Hb, int n) {
    int wave = threadIdx.x >> 6;
    int lane = threadIdx.x & 63;
    int i = blockIdx.x * 4 + wave;
    if (i >= n) return;
    int q   = lane >> 4;
    int sub = lane & 15;
    const uint4* P4 = (const uint4*)Pb;   // 16 uint4 per row
    float di = dinv[i];
    float a0 = 0.f, a1 = 0.f, a2 = 0.f, a3 = 0.f;
    float a4 = 0.f, a5 = 0.f, a6 = 0.f, a7 = 0.f;
    if (q == 0) {
        uint4 u = P4[(size_t)i * 16 + sub];
        a0 = di * blo(u.x); a1 = di * bhi(u.x); a2 = di * blo(u.y); a3 = di * bhi(u.y);
        a4 = di * blo(u.z); a5 = di * bhi(u.z); a6 = di * blo(u.w); a7 = di * bhi(u.w);
    }
    int2 r2 = rng[i];
    int e1 = r2.y;
    int e  = r2.x + q;
    while (e + 12 < e1) {
        int s0 = srt[e], s1 = srt[e + 4], s2 = srt[e + 8], s3 = srt[e + 12];
        float d0 = dinv[s0], d1 = dinv[s1], d2 = dinv[s2], d3 = dinv[s3];
        uint4 u0 = P4[(size_t)s0 * 16 + sub];
        uint4 u1 = P4[(size_t)s1 * 16 + sub];
        uint4 u2 = P4[(size_t)s2 * 16 + sub];
        uint4 u3 = P4[(size_t)s3 * 16 + sub];
        a0 = fmaf(d0, blo(u0.x), fmaf(d1, blo(u1.x), fmaf(d2, blo(u2.x), fmaf(d3, blo(u3.x), a0))));
        a1 = fmaf(d0, bhi(u0.x), fmaf(d1, bhi(u1.x), fmaf(d2, bhi(u2.x), fmaf(d3, bhi(u3.x), a1))));
        a2 = fmaf(d0, blo(u0.y), fmaf(d1, blo(u1.y), fmaf(d2, blo(u2.y), fmaf(d3, blo(u3.y), a2))));
        a3 = fmaf(d0, bhi(u0.y), fmaf(d1, bhi(u1.y), fmaf(d2, bhi(u2.y), fmaf(d3, bhi(u3.y), a3))));
        a4 = fmaf(d0, blo(u0.z), fmaf(d1, blo(u1.z), fmaf(d2, blo(u2.z), fmaf(d3, blo(u3.z), a4))));
        a5 = fmaf(d0, bhi(u0.z), fmaf(d1, bhi(u1.z), fmaf(d2, bhi(u2.z), fmaf(d3, bhi(u3.z), a5))));
        a6 = fmaf(d0, blo(u0.w), fmaf(d1, blo(u1.w), fmaf(d2, blo(u2.w), fmaf(d3, blo(u3.w), a6))));
        a7 = fmaf(d0, bhi(u0.w), fmaf(d1, bhi(u1.w), fmaf(d2, bhi(u2.w), fmaf(d3, bhi(u3.w), a7))));
        e += 16;
    }
    while (e < e1) {
        int s = srt[e];
        float ds = dinv[s];
        uint4 u = P4[(size_t)s * 16 + sub];
        a0 = fmaf(ds, blo(u.x), a0); a1 = fmaf(ds, bhi(u.x), a1);
        a2 = fmaf(ds, blo(u.y), a2); a3 = fmaf(ds, bhi(u.y), a3);
        a4 = fmaf(ds, blo(u.z), a4); a5 = fmaf(ds, bhi(u.z), a5);
        a6 = fmaf(ds, blo(u.w), a6); a7 = fmaf(ds, bhi(u.w), a7);
        e += 4;
    }
    a0 += __shfl_xor(a0, 16, 64); a0 += __shfl_xor(a0, 32, 64);
    a1 += __shfl_xor(a1, 16, 64); a1 += __shfl_xor(a1, 32, 64);
    a2 += __shfl_xor(a2, 16, 64); a2 += __shfl_xor(a2, 32, 64);
    a3 += __shfl_xor(a3, 16, 64); a3 += __shfl_xor(a3, 32, 64);
    a4 += __shfl_xor(a4, 16, 64); a4 += __shfl_xor(a4, 32, 64);
    a5 += __shfl_xor(a5, 16, 64); a5 += __shfl_xor(a5, 32, 64);
    a6 += __shfl_xor(a6, 16, 64); a6 += __shfl_xor(a6, 32, 64);
    a7 += __shfl_xor(a7, 16, 64); a7 += __shfl_xor(a7, 32, 64);
    if (q == 0) {
        int c = sub * 8;
        float4 b0 = *(const float4*)(bias + c);
        float4 b1 = *(const float4*)(bias + c + 4);
        uint4 o;
        o.x = pack2(fmaf(di, a0, b0.x), fmaf(di, a1, b0.y));
        o.y = pack2(fmaf(di, a2, b0.z), fmaf(di, a3, b0.w));
        o.z = pack2(fmaf(di, a4, b1.x), fmaf(di, a5, b1.y));
        o.w = pack2(fmaf(di, a6, b1.z), fmaf(di, a7, b1.w));
        *(uint4*)(Hb + (size_t)i * 128 + c) = o;
    }
}

// Fused tail: pool layer-2 inline + pool-reduce Gp1 + relu(G@Wl1+bl1)
// + @Wl2+bl2 + log_softmax. One block per graph.
__global__ __launch_bounds__(256) void k_mlp(const float* __restrict__ Gp1,
                                             const ushort* __restrict__ Hb,
                                             const int* __restrict__ batch, int n,
                                             const float* __restrict__ Wl1,
                                             const float* __restrict__ bl1,
                                             const float* __restrict__ Wl2,
                                             const float* __restrict__ bl2,
                                             float* __restrict__ out) {
    __shared__ float gs[256];
    __shared__ float zs[256];
    __shared__ float part[256];
    __shared__ float l[10];
    __shared__ int range[2];
    int g = blockIdx.x, j = threadIdx.x;
    if (j < 2) {
        int target = g + j;
        int lo = 0, hi = n;
        while (lo < hi) { int m = (lo + hi) >> 1; if (batch[m] < target) lo = m + 1; else hi = m; }
        range[j] = lo;
    }
    __syncthreads();
    {
        int c = j & 127, h = j >> 7;
        int r = range[0] + h, r1 = range[1];
        float s0 = 0.f, s1 = 0.f, s2 = 0.f, s3 = 0.f;
        for (; r + 6 < r1; r += 8) {
            s0 += __uint_as_float((uint)Hb[(size_t)r       * 128 + c] << 16);
            s1 += __uint_as_float((uint)Hb[(size_t)(r + 2) * 128 + c] << 16);
            s2 += __uint_as_float((uint)Hb[(size_t)(r + 4) * 128 + c] << 16);
            s3 += __uint_as_float((uint)Hb[(size_t)(r + 6) * 128 + c] << 16);
        }
        for (; r < r1; r += 2) s0 += __uint_as_float((uint)Hb[(size_t)r * 128 + c] << 16);
        part[j] = (s0 + s1) + (s2 + s3);
    }
    __syncthreads();
    if (j < 128) {
        const float* p = Gp1 + (size_t)g * 512 + j;
        gs[j] = (p[0] + p[128]) + (p[256] + p[384]);     // layer-1 pooled
        gs[128 + j] = part[j] + part[j + 128];           // layer-2 pooled
    }
    __syncthreads();
    float acc = bl1[j];
    for (int k = 0; k < 256; ++k) acc = fmaf(gs[k], Wl1[k * 256 + j], acc);
    zs[j] = fmaxf(acc, 0.f);
    __syncthreads();
    if (j < 10) {
        float a = bl2[j];
        for (int k = 0; k < 256; ++k) a = fmaf(zs[k], Wl2[k * 10 + j], a);
        l[j] = a;
    }
    __syncthreads();
    if (j < 10) {
        float m = l[0];
        for (int i = 1; i < 10; ++i) m = fmaxf(m, l[i]);
        float s = 0.f;
        for (int i = 0; i < 10; ++i) s += expf(l[i] - m);
        float lse = m + logf(s);
        out[g * 10 + j] = l[j];
        out[2560 + g * 10 + j] = l[j] - lse;
    }
}

static inline size_t alignup(size_t v) { return (v + 255) & ~(size_t)255; }

extern "C" void kernel_launch(void* const* d_in, const int* in_sizes, int n_in,
                              void* d_out, int out_size, void* d_ws, size_t ws_size,
                              hipStream_t stream) {
    const float* x    = (const float*)d_in[0];
    const int*   edge = (const int*)d_in[1];
    const int*   batch= (const int*)d_in[2];
    const float* W1   = (const float*)d_in[3];
    const float* b1   = (const float*)d_in[4];
    const float* W2   = (const float*)d_in[5];
    const float* b2   = (const float*)d_in[6];
    const float* Wl1  = (const float*)d_in[7];
    const float* bl1  = (const float*)d_in[8];
    const float* Wl2  = (const float*)d_in[9];
    const float* bl2  = (const float*)d_in[10];

    const int N = in_sizes[2];        // 50000
    const int E = in_sizes[1] / 2;    // 800000
    const int* srcIdx = edge;
    const int* dstIdx = edge + E;

    const int nb = (N + 255) >> 8;    // 196 buckets

    char* ws = (char*)d_ws;
    ushort* P     = (ushort*)ws; ws += alignup((size_t)N * DIMH * 2);
    ushort* Hb    = (ushort*)ws; ws += alignup((size_t)N * DIMH * 2);
    ushort* WT1   = (ushort*)ws; ws += alignup((size_t)128 * 128 * 2);
    ushort* WT2   = (ushort*)ws; ws += alignup((size_t)128 * 128 * 2);
    float*  dinv  = (float*)ws;  ws += alignup((size_t)N * 4);
    int2*   rng   = (int2*)ws;   ws += alignup((size_t)N * 8);
    int*    srt   = (int*)ws;    ws += alignup((size_t)nb * EBCAP * 4);
    uint*   ebuf  = (uint*)ws;   ws += alignup((size_t)nb * EBCAP * 4);
    int*    bcnt  = (int*)ws;    ws += alignup((size_t)256 * 4);
    float*  Gp1   = (float*)ws;  ws += alignup((size_t)1024 * 128 * 4);

    const int scnb  = (E + SCAT_CHUNK - 1) / SCAT_CHUNK;   // 782
    const int gemnb = (N + 63) / 64;                       // 782
    const int aggnb = (N + 3) / 4;

    // 1. zero bucket counters (kernel, not memset - see R13 header comment)
    k_zero<<<1, 256, 0, stream>>>(bcnt);
    // 2. scatter || wprep
    k_front<<<scnb + 128, 256, 0, stream>>>(srcIdx, dstIdx, bcnt, ebuf, E, scnb,
                                            W1, W2, WT1, WT2);
    // 3. layer-1 GEMM (f32 in) || per-bucket CSR + dinv
    k_g1csr<<<gemnb + nb, 256, 0, stream>>>(x, WT1, P, N, gemnb,
                                            ebuf, bcnt, dinv, rng, srt);
    // 4. layer-1 aggregate
    k_aggregate<<<aggnb, 256, 0, stream>>>(P, rng, srt, dinv, b1, Hb, N);
    // 5. layer-2 GEMM || layer-1 pool
    k_mid<<<gemnb + 1024, 256, 0, stream>>>(Hb, WT2, P, N, gemnb, batch, Gp1);
    // 6. layer-2 aggregate
    k_aggregate<<<aggnb, 256, 0, stream>>>(P, rng, srt, dinv, b2, Hb, N);
    // 7. fused pool2 + MLP head
    k_mlp<<<256, 256, 0, stream>>>(Gp1, Hb, batch, N, Wl1, bl1, Wl2, bl2, (float*)d_out);
}

// Round 14
// 162.808 us; speedup vs baseline: 1.0415x; 1.0415x over previous
//
#include <hip/hip_runtime.h>
#include <hip/hip_bf16.h>
#include <math.h>

// ---------------------------------------------------------------------------
// GCN forward: 2x GCNConv + global_add_pool + MLP + log_softmax.
// R14 = R12 config (best: 164.2us) + register-cached edges in scatter.
//   memset(bcnt) -> k_front(scatter || wprep) -> k_g1csr(gemm1-f32 || bcsr)
//   -> agg1 -> k_mid(gemm2 || pool1) -> agg2 -> k_mlp(pool2 + MLP + lsm)
// R13's k_zero + SCAT_CHUNK=1024 reverted (regressed +5.3us: tiny-fill
// theory disproven; 1024-chunk doubled global bcnt atomic contention).
// GEMMs write UNSCALED XW bf16; aggregate gathers dinv[s] per edge.
// ---------------------------------------------------------------------------

#define DIMH 128
#define EBCAP 8192   // per-bucket capacity (avg fill 4096)
#define SCAT_CHUNK 2048

typedef __attribute__((ext_vector_type(8))) short s16x8;
typedef __attribute__((ext_vector_type(4))) float f32x4;

__device__ inline ushort f2b(float f) {            // f32 -> bf16 RNE
    uint u = __float_as_uint(f);
    return (ushort)((u + 0x7fffu + ((u >> 16) & 1u)) >> 16);
}
__device__ inline uint pack2(float lo, float hi) {
    return (uint)f2b(lo) | ((uint)f2b(hi) << 16);
}
__device__ inline float blo(uint u) { return __uint_as_float(u << 16); }
__device__ inline float bhi(uint u) { return __uint_as_float(u & 0xffff0000u); }

// ---- front: scatter || wprep ----------------------------------------------
// bucket = dst>>8, record = (dst&255)<<24 | src   (needs N < 2^24)
__global__ __launch_bounds__(256) void k_front(const int* __restrict__ src,
                                               const int* __restrict__ dst,
                                               int* __restrict__ bcnt,
                                               uint* __restrict__ ebuf, int E, int scnb,
                                               const float* __restrict__ W1,
                                               const float* __restrict__ W2,
                                               ushort* __restrict__ WT1,
                                               ushort* __restrict__ WT2) {
    __shared__ int h[4][256];    // per-wave histogram / rank counters
    __shared__ int wb[4][256];   // per-wave bucket bases
    int blk = blockIdx.x;
    int t = threadIdx.x;
    if (blk < scnb) {
        int wave = t >> 6;
        h[0][t] = 0; h[1][t] = 0; h[2][t] = 0; h[3][t] = 0;
        __syncthreads();
        int e0 = blk * SCAT_CHUNK;
        int e1 = e0 + SCAT_CHUNK; if (e1 > E) e1 = E;
        // read this thread's <=8 edges once into registers
        int ed[8], es[8];
        int ne = 0;
#pragma unroll
        for (int k = 0; k < 8; ++k) {
            int e = e0 + t + k * 256;
            if (e < e1) { ed[ne] = dst[e]; es[ne] = src[e]; ++ne; }
        }
        for (int k = 0; k < ne; ++k)
            atomicAdd(&h[wave][ed[k] >> 8], 1);
        __syncthreads();
        {
            int h0 = h[0][t], h1 = h[1][t], h2 = h[2][t], h3 = h[3][t];
            int tot = h0 + h1 + h2 + h3;
            int gb = tot ? atomicAdd(&bcnt[t], tot) : 0;
            wb[0][t] = gb;
            wb[1][t] = gb + h0;
            wb[2][t] = gb + h0 + h1;
            wb[3][t] = gb + h0 + h1 + h2;
            h[0][t] = 0; h[1][t] = 0; h[2][t] = 0; h[3][t] = 0;
        }
        __syncthreads();
        for (int k = 0; k < ne; ++k) {
            int d = ed[k];
            int bk = d >> 8;
            int rank = wb[wave][bk] + atomicAdd(&h[wave][bk], 1);
            if (rank < EBCAP)
                ebuf[(size_t)bk * EBCAP + rank] = ((uint)(d & 255) << 24) | (uint)es[k];
        }
    } else {
        // ---- W1,W2 [128k][128n] f32 -> WT [128n][128k] bf16 ----
        int idx = (blk - scnb) * 256 + t;   // 128 blocks -> 32768
        const float* W = (idx < 16384) ? W1 : W2;
        ushort* WT = (idx < 16384) ? WT1 : WT2;
        int tt = idx & 16383;
        int k = tt >> 7, nn = tt & 127;
        WT[nn * 128 + k] = f2b(W[tt]);
    }
}

// ---- bcsr body: deg/dinv + local scan -> rng(int2) + dense srt ------------
__device__ __forceinline__ void bcsr_body(const uint* __restrict__ ebuf,
                                          const int* __restrict__ bcnt,
                                          float* __restrict__ dinv,
                                          int2* __restrict__ rng,
                                          int* __restrict__ srt, int n,
                                          int b, int* cnt, int* wsum, int* stage) {
    int t = threadIdx.x;
    int c = bcnt[b]; if (c > EBCAP) c = EBCAP;
    size_t B = (size_t)b * EBCAP;
    cnt[t] = 0;
    __syncthreads();
    for (int i = t; i < c; i += 256)
        atomicAdd(&cnt[ebuf[B + i] >> 24], 1);
    __syncthreads();
    int v = cnt[t];
    int incl = v;
    for (int k = 1; k < 64; k <<= 1) {
        int u = __shfl_up(incl, k, 64);
        if ((t & 63) >= k) incl += u;
    }
    if ((t & 63) == 63) wsum[t >> 6] = incl;
    __syncthreads();
    int add = 0;
    for (int j = 0; j < (t >> 6); ++j) add += wsum[j];
    incl += add;
    int loc = incl - v;
    int node = b * 256 + t;
    if (node < n) {
        dinv[node] = rsqrtf((float)(v + 1));   // +1 self-loop
        rng[node] = make_int2((int)B + loc, (int)B + loc + v);
    }
    cnt[t] = loc;                    // reuse as cursor
    __syncthreads();
    for (int i = t; i < c; i += 256) {
        uint r = ebuf[B + i];
        int p = atomicAdd(&cnt[r >> 24], 1);
        stage[p] = (int)(r & 0xffffffu);
    }
    __syncthreads();
    for (int i = t; i < c; i += 256) srt[B + i] = stage[i];
}

// ---- GEMM body: P[64 rows][128] bf16 = Xin @ W (UNSCALED), WT[n][k] -------
template<bool F32IN>
__device__ __forceinline__ void gemm_body(const void* __restrict__ Xin,
                                          const ushort* __restrict__ WT,
                                          ushort* __restrict__ P, int n,
                                          int blk, ushort* lds) {
    ushort* Xs = lds;
    ushort* Ws = lds + 64 * 128;
    const int tid = threadIdx.x;
    const int row0 = blk * 64;
    if (F32IN) {
        const float* Xf = (const float*)Xin;
        for (int ci = tid; ci < 2048; ci += 256) {
            int r = ci >> 5, c8 = ci & 31;
            uint dstB = (uint)(r * 256 + c8 * 8) ^ (uint)((r & 7) << 4);
            uint2 v = make_uint2(0u, 0u);
            if (row0 + r < n) {
                float4 f = *(const float4*)(Xf + (size_t)(row0 + r) * 128 + c8 * 4);
                v.x = pack2(f.x, f.y); v.y = pack2(f.z, f.w);
            }
            *(uint2*)((char*)Xs + dstB) = v;
        }
    } else {
        const ushort* Xb = (const ushort*)Xin;
        for (int ci = tid; ci < 1024; ci += 256) {
            int r = ci >> 4, c16 = ci & 15;
            uint dstB = (uint)(r * 256 + c16 * 16) ^ (uint)((r & 7) << 4);
            uint4 v = make_uint4(0u, 0u, 0u, 0u);
            if (row0 + r < n) v = *(const uint4*)(Xb + (size_t)(row0 + r) * 128 + c16 * 8);
            *(uint4*)((char*)Xs + dstB) = v;
        }
    }
    for (int ci = tid; ci < 2048; ci += 256) {
        int r = ci >> 4, c16 = ci & 15;
        uint dstB = (uint)(r * 256 + c16 * 16) ^ (uint)((r & 7) << 4);
        *(uint4*)((char*)Ws + dstB) = *(const uint4*)(WT + (size_t)r * 128 + c16 * 8);
    }
    __syncthreads();
    const int wave = tid >> 6, lane = tid & 63;
    const int l15 = lane & 15, g = lane >> 4;
    f32x4 acc[8];
#pragma unroll
    for (int nt = 0; nt < 8; ++nt) acc[nt] = (f32x4){0.f, 0.f, 0.f, 0.f};
    const int tr = wave * 16 + l15;
    const uint aswz = (uint)((tr & 7) << 4);
#pragma unroll
    for (int kk = 0; kk < 4; ++kk) {
        uint aB = ((uint)(tr * 256 + kk * 64 + g * 16)) ^ aswz;
        s16x8 afrag = *(const s16x8*)((const char*)Xs + aB);
#pragma unroll
        for (int nt = 0; nt < 8; ++nt) {
            int wr = nt * 16 + l15;
            uint bB = ((uint)(wr * 256 + kk * 64 + g * 16)) ^ ((uint)((wr & 7) << 4));
            s16x8 bfrag = *(const s16x8*)((const char*)Ws + bB);
            acc[nt] = __builtin_amdgcn_mfma_f32_16x16x32_bf16(afrag, bfrag, acc[nt], 0, 0, 0);
        }
    }
#pragma unroll
    for (int nt = 0; nt < 8; ++nt) {
        int gcol = nt * 16 + l15;
#pragma unroll
        for (int reg = 0; reg < 4; ++reg) {
            int grow = row0 + wave * 16 + g * 4 + reg;
            if (grow < n) P[(size_t)grow * 128 + gcol] = f2b(acc[nt][reg]);
        }
    }
}

// ---- g1csr: gemm1 (f32 input, blocks < gemnb) || bcsr ---------------------
__global__ __launch_bounds__(256) void k_g1csr(const float* __restrict__ x,
                                               const ushort* __restrict__ WT1,
                                               ushort* __restrict__ P, int n, int gemnb,
                                               const uint* __restrict__ ebuf,
                                               const int* __restrict__ bcnt,
                                               float* __restrict__ dinv,
                                               int2* __restrict__ rng,
                                               int* __restrict__ srt) {
    __shared__ ushort lds[64 * 128 + 128 * 128];   // 48KB; bcsr carves from it
    int blk = blockIdx.x;
    if (blk < gemnb) {
        gemm_body<true>(x, WT1, P, n, blk, lds);
    } else {
        int* cnt   = (int*)lds;          // 256 ints
        int* wsum  = cnt + 256;          // 8 ints
        int* stage = wsum + 8;           // EBCAP ints
        bcsr_body(ebuf, bcnt, dinv, rng, srt, n, blk - gemnb, cnt, wsum, stage);
    }
}

// ---- pool body: block = (graph g, quarter q); 8 row-streams, stride 8 -----
__device__ __forceinline__ void pool_body(const ushort* __restrict__ Hb,
                                          const int* __restrict__ batch,
                                          float* __restrict__ Gpart, int n,
                                          int blk, int* range, float* part) {
    int g = blk >> 2, q = blk & 3;
    if (threadIdx.x < 2) {
        int target = g + threadIdx.x;
        int lo = 0, hi = n;
        while (lo < hi) { int m = (lo + hi) >> 1; if (batch[m] < target) lo = m + 1; else hi = m; }
        range[threadIdx.x] = lo;
    }
    __syncthreads();
    int c = threadIdx.x & 127, h = threadIdx.x >> 7;
    int r = range[0] + q * 2 + h, r1 = range[1];
    float s0 = 0.f, s1 = 0.f;
    for (; r + 8 < r1; r += 16) {
        s0 += __uint_as_float((uint)Hb[(size_t)r       * 128 + c] << 16);
        s1 += __uint_as_float((uint)Hb[(size_t)(r + 8) * 128 + c] << 16);
    }
    for (; r < r1; r += 8) s0 += __uint_as_float((uint)Hb[(size_t)r * 128 + c] << 16);
    part[threadIdx.x] = s0 + s1;
    __syncthreads();
    if (threadIdx.x < 128)
        Gpart[(size_t)blk * 128 + threadIdx.x] = part[threadIdx.x] + part[threadIdx.x + 128];
}

// ---- mid: gemm2 (bf16 input, blocks < gemnb) || pool1 ---------------------
__global__ __launch_bounds__(256) void k_mid(const ushort* __restrict__ Hb,
                                             const ushort* __restrict__ WT,
                                             ushort* __restrict__ P, int n, int gemnb,
                                             const int* __restrict__ batch,
                                             float* __restrict__ Gpart) {
    __shared__ ushort lds[64 * 128 + 128 * 128];   // 48KB (gemm path)
    __shared__ int range[2];
    __shared__ float part[256];
    int blk = blockIdx.x;
    if (blk < gemnb) {
        gemm_body<false>(Hb, WT, P, n, blk, lds);
    } else {
        pool_body(Hb, batch, Gpart, n, blk - gemnb, range, part);
    }
}

// H[i] = bf16( dinv[i]*(dinv[i]*P[i] + sum_s dinv[s]*P[s]) + bias ).
// P bf16 UNSCALED, 256B/row; dinv gathered per edge (L2-resident, 200KB).
__global__ __launch_bounds__(256) void k_aggregate(const ushort* __restrict__ Pb,
                                                   const int2* __restrict__ rng,
                                                   const int* __restrict__ srt,
                                                   const float* __restrict__ dinv,
                                                   const float* __restrict__ bias,
                                                   ushort* __restrict__ Hb, int n) {
    int wave = threadIdx.x >> 6;
    int lane = threadIdx.x & 63;
    int i = blockIdx.x * 4 + wave;
    if (i >= n) return;
    int q   = lane >> 4;
    int sub = lane & 15;
    const uint4* P4 = (const uint4*)Pb;   // 16 uint4 per row
    float di = dinv[i];
    float a0 = 0.f, a1 = 0.f, a2 = 0.f, a3 = 0.f;
    float a4 = 0.f, a5 = 0.f, a6 = 0.f, a7 = 0.f;
    if (q == 0) {
        uint4 u = P4[(size_t)i * 16 + sub];
        a0 = di * blo(u.x); a1 = di * bhi(u.x); a2 = di * blo(u.y); a3 = di * bhi(u.y);
        a4 = di * blo(u.z); a5 = di * bhi(u.z); a6 = di * blo(u.w); a7 = di * bhi(u.w);
    }
    int2 r2 = rng[i];
    int e1 = r2.y;
    int e  = r2.x + q;
    while (e + 12 < e1) {
        int s0 = srt[e], s1 = srt[e + 4], s2 = srt[e + 8], s3 = srt[e + 12];
        float d0 = dinv[s0], d1 = dinv[s1], d2 = dinv[s2], d3 = dinv[s3];
        uint4 u0 = P4[(size_t)s0 * 16 + sub];
        uint4 u1 = P4[(size_t)s1 * 16 + sub];
        uint4 u2 = P4[(size_t)s2 * 16 + sub];
        uint4 u3 = P4[(size_t)s3 * 16 + sub];
        a0 = fmaf(d0, blo(u0.x), fmaf(d1, blo(u1.x), fmaf(d2, blo(u2.x), fmaf(d3, blo(u3.x), a0))));
        a1 = fmaf(d0, bhi(u0.x), fmaf(d1, bhi(u1.x), fmaf(d2, bhi(u2.x), fmaf(d3, bhi(u3.x), a1))));
        a2 = fmaf(d0, blo(u0.y), fmaf(d1, blo(u1.y), fmaf(d2, blo(u2.y), fmaf(d3, blo(u3.y), a2))));
        a3 = fmaf(d0, bhi(u0.y), fmaf(d1, bhi(u1.y), fmaf(d2, bhi(u2.y), fmaf(d3, bhi(u3.y), a3))));
        a4 = fmaf(d0, blo(u0.z), fmaf(d1, blo(u1.z), fmaf(d2, blo(u2.z), fmaf(d3, blo(u3.z), a4))));
        a5 = fmaf(d0, bhi(u0.z), fmaf(d1, bhi(u1.z), fmaf(d2, bhi(u2.z), fmaf(d3, bhi(u3.z), a5))));
        a6 = fmaf(d0, blo(u0.w), fmaf(d1, blo(u1.w), fmaf(d2, blo(u2.w), fmaf(d3, blo(u3.w), a6))));
        a7 = fmaf(d0, bhi(u0.w), fmaf(d1, bhi(u1.w), fmaf(d2, bhi(u2.w), fmaf(d3, bhi(u3.w), a7))));
        e += 16;
    }
    while (e < e1) {
        int s = srt[e];
        float ds = dinv[s];
        uint4 u = P4[(size_t)s * 16 + sub];
        a0 = fmaf(ds, blo(u.x), a0); a1 = fmaf(ds, bhi(u.x), a1);
        a2 = fmaf(ds, blo(u.y), a2); a3 = fmaf(ds, bhi(u.y), a3);
        a4 = fmaf(ds, blo(u.z), a4); a5 = fmaf(ds, bhi(u.z), a5);
        a6 = fmaf(ds, blo(u.w), a6); a7 = fmaf(ds, bhi(u.w), a7);
        e += 4;
    }
    a0 += __shfl_xor(a0, 16, 64); a0 += __shfl_xor(a0, 32, 64);
    a1 += __shfl_xor(a1, 16, 64); a1 += __shfl_xor(a1, 32, 64);
    a2 += __shfl_xor(a2, 16, 64); a2 += __shfl_xor(a2, 32, 64);
    a3 += __shfl_xor(a3, 16, 64); a3 += __shfl_xor(a3, 32, 64);
    a4 += __shfl_xor(a4, 16, 64); a4 += __shfl_xor(a4, 32, 64);
    a5 += __shfl_xor(a5, 16, 64); a5 += __shfl_xor(a5, 32, 64);
    a6 += __shfl_xor(a6, 16, 64); a6 += __shfl_xor(a6, 32, 64);
    a7 += __shfl_xor(a7, 16, 64); a7 += __shfl_xor(a7, 32, 64);
    if (q == 0) {
        int c = sub * 8;
        float4 b0 = *(const float4*)(bias + c);
        float4 b1 = *(const float4*)(bias + c + 4);
        uint4 o;
        o.x = pack2(fmaf(di, a0, b0.x), fmaf(di, a1, b0.y));
        o.y = pack2(fmaf(di, a2, b0.z), fmaf(di, a3, b0.w));
        o.z = pack2(fmaf(di, a4, b1.x), fmaf(di, a5, b1.y));
        o.w = pack2(fmaf(di, a6, b1.z), fmaf(di, a7, b1.w));
        *(uint4*)(Hb + (size_t)i * 128 + c) = o;
    }
}

// Fused tail: pool layer-2 inline + pool-reduce Gp1 + relu(G@Wl1+bl1)
// + @Wl2+bl2 + log_softmax. One block per graph.
__global__ __launch_bounds__(256) void k_mlp(const float* __restrict__ Gp1,
                                             const ushort* __restrict__ Hb,
                                             const int* __restrict__ batch, int n,
                                             const float* __restrict__ Wl1,
                                             const float* __restrict__ bl1,
                                             const float* __restrict__ Wl2,
                                             const float* __restrict__ bl2,
                                             float* __restrict__ out) {
    __shared__ float gs[256];
    __shared__ float zs[256];
    __shared__ float part[256];
    __shared__ float l[10];
    __shared__ int range[2];
    int g = blockIdx.x, j = threadIdx.x;
    if (j < 2) {
        int target = g + j;
        int lo = 0, hi = n;
        while (lo < hi) { int m = (lo + hi) >> 1; if (batch[m] < target) lo = m + 1; else hi = m; }
        range[j] = lo;
    }
    __syncthreads();
    {
        int c = j & 127, h = j >> 7;
        int r = range[0] + h, r1 = range[1];
        float s0 = 0.f, s1 = 0.f, s2 = 0.f, s3 = 0.f;
        for (; r + 6 < r1; r += 8) {
            s0 += __uint_as_float((uint)Hb[(size_t)r       * 128 + c] << 16);
            s1 += __uint_as_float((uint)Hb[(size_t)(r + 2) * 128 + c] << 16);
            s2 += __uint_as_float((uint)Hb[(size_t)(r + 4) * 128 + c] << 16);
            s3 += __uint_as_float((uint)Hb[(size_t)(r + 6) * 128 + c] << 16);
        }
        for (; r < r1; r += 2) s0 += __uint_as_float((uint)Hb[(size_t)r * 128 + c] << 16);
        part[j] = (s0 + s1) + (s2 + s3);
    }
    __syncthreads();
    if (j < 128) {
        const float* p = Gp1 + (size_t)g * 512 + j;
        gs[j] = (p[0] + p[128]) + (p[256] + p[384]);     // layer-1 pooled
        gs[128 + j] = part[j] + part[j + 128];           // layer-2 pooled
    }
    __syncthreads();
    float acc = bl1[j];
    for (int k = 0; k < 256; ++k) acc = fmaf(gs[k], Wl1[k * 256 + j], acc);
    zs[j] = fmaxf(acc, 0.f);
    __syncthreads();
    if (j < 10) {
        float a = bl2[j];
        for (int k = 0; k < 256; ++k) a = fmaf(zs[k], Wl2[k * 10 + j], a);
        l[j] = a;
    }
    __syncthreads();
    if (j < 10) {
        float m = l[0];
        for (int i = 1; i < 10; ++i) m = fmaxf(m, l[i]);
        float s = 0.f;
        for (int i = 0; i < 10; ++i) s += expf(l[i] - m);
        float lse = m + logf(s);
        out[g * 10 + j] = l[j];
        out[2560 + g * 10 + j] = l[j] - lse;
    }
}

static inline size_t alignup(size_t v) { return (v + 255) & ~(size_t)255; }

extern "C" void kernel_launch(void* const* d_in, const int* in_sizes, int n_in,
                              void* d_out, int out_size, void* d_ws, size_t ws_size,
                              hipStream_t stream) {
    const float* x    = (const float*)d_in[0];
    const int*   edge = (const int*)d_in[1];
    const int*   batch= (const int*)d_in[2];
    const float* W1   = (const float*)d_in[3];
    const float* b1   = (const float*)d_in[4];
    const float* W2   = (const float*)d_in[5];
    const float* b2   = (const float*)d_in[6];
    const float* Wl1  = (const float*)d_in[7];
    const float* bl1  = (const float*)d_in[8];
    const float* Wl2  = (const float*)d_in[9];
    const float* bl2  = (const float*)d_in[10];

    const int N = in_sizes[2];        // 50000
    const int E = in_sizes[1] / 2;    // 800000
    const int* srcIdx = edge;
    const int* dstIdx = edge + E;

    const int nb = (N + 255) >> 8;    // 196 buckets

    char* ws = (char*)d_ws;
    ushort* P     = (ushort*)ws; ws += alignup((size_t)N * DIMH * 2);
    ushort* Hb    = (ushort*)ws; ws += alignup((size_t)N * DIMH * 2);
    ushort* WT1   = (ushort*)ws; ws += alignup((size_t)128 * 128 * 2);
    ushort* WT2   = (ushort*)ws; ws += alignup((size_t)128 * 128 * 2);
    float*  dinv  = (float*)ws;  ws += alignup((size_t)N * 4);
    int2*   rng   = (int2*)ws;   ws += alignup((size_t)N * 8);
    int*    srt   = (int*)ws;    ws += alignup((size_t)nb * EBCAP * 4);
    uint*   ebuf  = (uint*)ws;   ws += alignup((size_t)nb * EBCAP * 4);
    int*    bcnt  = (int*)ws;    ws += alignup((size_t)256 * 4);
    float*  Gp1   = (float*)ws;  ws += alignup((size_t)1024 * 128 * 4);

    const int scnb  = (E + SCAT_CHUNK - 1) / SCAT_CHUNK;   // 391
    const int gemnb = (N + 63) / 64;                       // 782
    const int aggnb = (N + 3) / 4;

    // 1. zero bucket counters
    hipMemsetAsync(bcnt, 0, (size_t)256 * 4, stream);
    // 2. scatter || wprep
    k_front<<<scnb + 128, 256, 0, stream>>>(srcIdx, dstIdx, bcnt, ebuf, E, scnb,
                                            W1, W2, WT1, WT2);
    // 3. layer-1 GEMM (f32 in) || per-bucket CSR + dinv
    k_g1csr<<<gemnb + nb, 256, 0, stream>>>(x, WT1, P, N, gemnb,
                                            ebuf, bcnt, dinv, rng, srt);
    // 4. layer-1 aggregate
    k_aggregate<<<aggnb, 256, 0, stream>>>(P, rng, srt, dinv, b1, Hb, N);
    // 5. layer-2 GEMM || layer-1 pool
    k_mid<<<gemnb + 1024, 256, 0, stream>>>(Hb, WT2, P, N, gemnb, batch, Gp1);
    // 6. layer-2 aggregate
    k_aggregate<<<aggnb, 256, 0, stream>>>(P, rng, srt, dinv, b2, Hb, N);
    // 7. fused pool2 + MLP head
    k_mlp<<<256, 256, 0, stream>>>(Gp1, Hb, batch, N, Wl1, bl1, Wl2, bl2, (float*)d_out);
}